// Round 16
// baseline (36.288 us; speedup 1.0000x reference)
//
#include <hip/hip_runtime.h>

typedef _Float16 half8  __attribute__((ext_vector_type(8)));
typedef __fp16   fp16x2 __attribute__((ext_vector_type(2)));
typedef unsigned u32x2  __attribute__((ext_vector_type(2)));
typedef float    f32x16 __attribute__((ext_vector_type(16)));

#define T16BITS 0x1C19u   // f16 bits of ~4.001e-3 (residual stop threshold)
#define KMAX    20        // iteration cap (cap never binds in practice; max iters ~<=20)
// descending compare-exchange
#define CE(a,b) { float _hi = fmaxf(a,b), _lo = fminf(a,b); a = _hi; b = _lo; }

// permlane32 swap: a' = {a.lo, b.lo}, b' = {a.hi, b.hi}  (lo/hi = lane halves)
static __device__ __forceinline__ void plswap(unsigned &a, unsigned &b) {
#if __has_builtin(__builtin_amdgcn_permlane32_swap)
    u32x2 r = __builtin_amdgcn_permlane32_swap(a, b, false, false);
    a = r[0]; b = r[1];
#else
    unsigned ao, bo;
    asm("v_mov_b32 %0, %2\n\t"
        "v_mov_b32 %1, %3\n\t"
        "v_permlane32_swap_b32 %0, %1"
        : "=&v"(ao), "=&v"(bo) : "v"(a), "v"(b));
    a = ao; b = bo;
#endif
}
static __device__ __forceinline__ void plswapf(float &a, float &b) {
    union { float f; unsigned u; } ua, ub;
    ua.f = a; ub.f = b;
    plswap(ua.u, ub.u);
    a = ua.f; b = ub.f;
}

static __device__ __forceinline__ unsigned pkrtz(float a, float b) {
    union { fp16x2 h; unsigned u; } x;
    x.h = __builtin_amdgcn_cvt_pkrtz(a, b);   // lo = a, hi = b
    return x.u;
}
static __device__ __forceinline__ fp16x2 u2h(unsigned v) {
    union { unsigned u; fp16x2 h; } x; x.u = v; return x.h;
}
static __device__ __forceinline__ unsigned h2u(fp16x2 v) {
    union { fp16x2 h; unsigned u; } x; x.h = v; return x.u;
}
// pack to f16 then packed leaky-relu: max(p, p*0.1)
static __device__ __forceinline__ unsigned pk_leaky(float a, float b, fp16x2 slope) {
    union { fp16x2 h; unsigned u; } x;
    x.h = __builtin_amdgcn_cvt_pkrtz(a, b);
    fp16x2 m = x.h * slope;
    x.h = __builtin_elementwise_max(x.h, m);
    return x.u;
}
static __device__ __forceinline__ unsigned pk_rne(float a, float b) {
    union { _Float16 h[2]; unsigned u; } x;
    x.h[0] = (_Float16)a; x.h[1] = (_Float16)b;
    return x.u;
}
static __device__ __forceinline__ half8 mk8(unsigned a, unsigned b, unsigned c, unsigned d) {
    union { unsigned u[4]; half8 h; } x;
    x.u[0] = a; x.u[1] = b; x.u[2] = c; x.u[3] = d;
    return x.h;
}
// extract word i (compile-time const) of a half8
static __device__ __forceinline__ unsigned getw(half8 v, int i) {
    union { half8 h; unsigned u[4]; } x; x.h = v; return x.u[i];
}

__launch_bounds__(64, 4)
__global__ void nfpn_mfma_kernel(const float* __restrict__ dptr,
                                 const float* __restrict__ W1, const float* __restrict__ b1,
                                 const float* __restrict__ W2, const float* __restrict__ b2,
                                 const float* __restrict__ W3, const float* __restrict__ b3,
                                 float* __restrict__ out, long long B)
{
    const int lane = threadIdx.x;        // 64-thread block = exactly one wave
    const int hi   = lane >> 5;          // lane half (0: lanes 0-31, 1: lanes 32-63)
    const int col  = lane & 31;          // MFMA column / M-row index
    const bool ishi = (hi != 0);
    const long long wid = blockIdx.x;    // one wave per block -> finer scheduling/backfill
    // two independent row-groups per wave: G0 = rows [wid*128, +64), G1 = +64
    const long long own0 = wid * 128 + (long long)hi * 32 + col;
    const long long own1 = own0 + 64;
    if (own1 >= B) return;               // B % 128 == 0 -> wave-uniform

    // ---------------- A1 fragments (per-tile k conventions, SHARED by groups) ---
    // slot k = 8*hi + e, e = 0..7  (slot-paired with B; any shared relabel cancels)
    // tileE (even): k0..5 = u, k6..11 = Qd, k12 = b2-slot(1.0)   (u on LO lane words)
    // tileO (odd):  k0..5 = Qd, k6 = b2-slot(1.0), k8..13 = u    (u on HI lane words)
    half8 aW2t0, aW2t1;
    {
        unsigned w0[4], w1[4];
        const bool jv = (col < 30);
        const int jc = jv ? col : 0;
        #pragma unroll
        for (int i = 0; i < 4; ++i) {
            const int k0 = 8 * hi + 2 * i, k1 = k0 + 1;
            float x0 = (k0 < 12) ? W2[jc * 12 + k0] : ((k0 == 12) ? b2[jc] : 0.0f);
            float y0 = (k1 < 12) ? W2[jc * 12 + k1] : ((k1 == 12) ? b2[jc] : 0.0f);
            float x1 = (k0 < 6) ? W2[jc * 12 + 6 + k0] : ((k0 == 6) ? b2[jc] : ((k0 >= 8 && k0 < 14) ? W2[jc * 12 + (k0 - 8)] : 0.0f));
            float y1 = (k1 < 6) ? W2[jc * 12 + 6 + k1] : ((k1 == 6) ? b2[jc] : ((k1 >= 8 && k1 < 14) ? W2[jc * 12 + (k1 - 8)] : 0.0f));
            if (!jv) { x0 = 0.0f; y0 = 0.0f; x1 = 0.0f; y1 = 0.0f; }
            w0[i] = pk_rne(x0, y0);
            w1[i] = pk_rne(x1, y1);
        }
        aW2t0 = mk8(w0[0], w0[1], w0[2], w0[3]);
        aW2t1 = mk8(w1[0], w1[1], w1[2], w1[3]);
    }

    // ---------------- A2 fragments: k-map = P's NATURAL C-layout word order -----
    // sigma(hi,e) = 4*hi + (e<4 ? e : e+4); A2a row = sigma, A2b row = 16+sigma
    // (negated W3, -b3 at row 30 -> MFMA2 output is projection input v directly)
    half8 aW3a, aW3b;
    {
        unsigned pa[4], pb[4];
        const bool mv = (col < 6);
        const int mc = mv ? col : 0;
        #pragma unroll
        for (int i = 0; i < 4; ++i) {
            const int e0 = 2 * i, e1 = 2 * i + 1;
            const int r0 = 4 * hi + (e0 < 4 ? e0 : e0 + 4);
            const int r1 = 4 * hi + (e1 < 4 ? e1 : e1 + 4);
            float xa = -W3[mc * 30 + r0];    // r0,r1 in [0,16)
            float ya = -W3[mc * 30 + r1];
            if (!mv) { xa = 0.0f; ya = 0.0f; }
            pa[i] = pk_rne(xa, ya);
            const int rb0 = 16 + r0, rb1 = 16 + r1;
            float xb = (rb0 < 30) ? -W3[mc * 30 + rb0] : ((rb0 == 30) ? -b3[mc] : 0.0f);
            float yb = (rb1 < 30) ? -W3[mc * 30 + rb1] : ((rb1 == 30) ? -b3[mc] : 0.0f);
            if (!mv) { xb = 0.0f; yb = 0.0f; }
            pb[i] = pk_rne(xb, yb);
        }
        aW3a = mk8(pa[0], pa[1], pa[2], pa[3]);
        aW3b = mk8(pb[0], pb[1], pb[2], pb[3]);
    }

    const unsigned ONEH = 0x00003C00u;      // f16 {1.0, 0.0}
    const fp16x2 slope = { (__fp16)0.1f, (__fp16)0.1f };
    const fp16x2 zero2 = { (__fp16)0.0f, (__fp16)0.0f };

    // ---------------- initial uf build per group (Qd inside the tuples) ---------
    half8 uf0, uf1, uf2, uf3;
    {
        const float dA0 = dptr[own0 * 3 + 0], dA1 = dptr[own0 * 3 + 1], dA2 = dptr[own0 * 3 + 2];
        const float dB0 = dptr[own1 * 3 + 0], dB1 = dptr[own1 * 3 + 1], dB2 = dptr[own1 * 3 + 2];
        float qa0[6], qa1[6], qb0[6], qb1[6];
        #pragma unroll
        for (int m = 0; m < 6; ++m) {
            const float w0v = W1[m * 3 + 0], w1v = W1[m * 3 + 1], w2v = W1[m * 3 + 2], bb = b1[m];
            float qa = fmaf(w0v, dA0, fmaf(w1v, dA1, fmaf(w2v, dA2, bb)));
            float qb = fmaf(w0v, dB0, fmaf(w1v, dB1, fmaf(w2v, dB2, bb)));
            qa0[m] = __shfl(qa, col);        // G0 tile0 col's Qd[m]
            qa1[m] = __shfl(qa, 32 + col);   // G0 tile1
            qb0[m] = __shfl(qb, col);        // G1 tile0
            qb1[m] = __shfl(qb, 32 + col);   // G1 tile1
        }
        const unsigned qdA0 = pkrtz(qa0[0], qa0[1]), qdB0 = pkrtz(qa0[2], qa0[3]), qdC0 = pkrtz(qa0[4], qa0[5]);
        const unsigned qdA1 = pkrtz(qa1[0], qa1[1]), qdB1 = pkrtz(qa1[2], qa1[3]), qdC1 = pkrtz(qa1[4], qa1[5]);
        const unsigned qdA2 = pkrtz(qb0[0], qb0[1]), qdB2 = pkrtz(qb0[2], qb0[3]), qdC2 = pkrtz(qb0[4], qb0[5]);
        const unsigned qdA3 = pkrtz(qb1[0], qb1[1]), qdB3 = pkrtz(qb1[2], qb1[3]), qdC3 = pkrtz(qb1[4], qb1[5]);
        uf0 = mk8(ishi ? qdB0 : 0u, ishi ? qdC0 : 0u, ishi ? ONEH : 0u, qdA0);
        uf1 = mk8(ishi ? 0u : qdA1, ishi ? 0u : qdB1, ishi ? 0u : qdC1, ONEH);
        uf2 = mk8(ishi ? qdB2 : 0u, ishi ? qdC2 : 0u, ishi ? ONEH : 0u, qdA2);
        uf3 = mk8(ishi ? 0u : qdA3, ishi ? 0u : qdB3, ishi ? 0u : qdC3, ONEH);
    }

    // shared zero C-operand
    f32x16 z16;
    #pragma unroll
    for (int i = 0; i < 16; ++i) z16[i] = 0.0f;

    // packed u per group: (u0,u1)(u2,u3)(u4,u5)
    unsigned qA0 = 0, qA1 = 0, qA2 = 0;     // G0
    unsigned qB0 = 0, qB1 = 0, qB2 = 0;     // G1

    bool conv = false;
    int k = 0;
    #pragma unroll 1
    while (true) {
        ++k;
        // ---- G0: MFMA1 both tiles -> P0/P1 (P2/P3 NOT yet live: halves P peak) --
        unsigned P0[8], P1[8];
        {
            f32x16 h = __builtin_amdgcn_mfma_f32_32x32x16_f16(aW2t0, uf0, z16, 0, 0, 0);
            #pragma unroll
            for (int i = 0; i < 8; ++i) P0[i] = pk_leaky(h[2 * i], h[2 * i + 1], slope);
        }
        {
            f32x16 h = __builtin_amdgcn_mfma_f32_32x32x16_f16(aW2t1, uf1, z16, 0, 0, 0);
            #pragma unroll
            for (int i = 0; i < 8; ++i) P1[i] = pk_leaky(h[2 * i], h[2 * i + 1], slope);
        }
        P0[7] = ishi ? ONEH : P0[7];
        P1[7] = ishi ? ONEH : P1[7];

        // ---- G0 MFMA2 chain (G1's independent MFMA1 below fills its shadow) ----
        float v0, v1, v2, v3, v4, v5;
        {
            f32x16 acc = __builtin_amdgcn_mfma_f32_32x32x16_f16(aW3a, mk8(P0[0], P0[1], P0[2], P0[3]), z16, 0, 0, 0);
            acc = __builtin_amdgcn_mfma_f32_32x32x16_f16(aW3b, mk8(P0[4], P0[5], P0[6], P0[7]), acc, 0, 0, 0);
            v0 = acc[0]; v1 = acc[1]; v2 = acc[2]; v3 = acc[3];
            acc = __builtin_amdgcn_mfma_f32_32x32x16_f16(aW3a, mk8(P1[0], P1[1], P1[2], P1[3]), z16, 0, 0, 0);
            acc = __builtin_amdgcn_mfma_f32_32x32x16_f16(aW3b, mk8(P1[4], P1[5], P1[6], P1[7]), acc, 0, 0, 0);
            v4 = acc[0]; v5 = acc[1];
            float y2 = acc[2], y3 = acc[3];
            plswapf(v0, v4); plswapf(v1, v5); plswapf(v2, y2); plswapf(v3, y3);
        }

        // ---- G1: MFMA1 both tiles -> P2/P3 (reuses P0/P1's register space) -----
        unsigned P2[8], P3[8];
        {
            f32x16 h = __builtin_amdgcn_mfma_f32_32x32x16_f16(aW2t0, uf2, z16, 0, 0, 0);
            #pragma unroll
            for (int i = 0; i < 8; ++i) P2[i] = pk_leaky(h[2 * i], h[2 * i + 1], slope);
        }
        {
            f32x16 h = __builtin_amdgcn_mfma_f32_32x32x16_f16(aW2t1, uf3, z16, 0, 0, 0);
            #pragma unroll
            for (int i = 0; i < 8; ++i) P3[i] = pk_leaky(h[2 * i], h[2 * i + 1], slope);
        }
        P2[7] = ishi ? ONEH : P2[7];
        P3[7] = ishi ? ONEH : P3[7];

        // ---- G1 MFMA2 chain (G0's projection below fills its shadow) -----------
        float w0, w1, w2, w3, w4, w5;
        {
            f32x16 acc = __builtin_amdgcn_mfma_f32_32x32x16_f16(aW3a, mk8(P2[0], P2[1], P2[2], P2[3]), z16, 0, 0, 0);
            acc = __builtin_amdgcn_mfma_f32_32x32x16_f16(aW3b, mk8(P2[4], P2[5], P2[6], P2[7]), acc, 0, 0, 0);
            w0 = acc[0]; w1 = acc[1]; w2 = acc[2]; w3 = acc[3];
            acc = __builtin_amdgcn_mfma_f32_32x32x16_f16(aW3a, mk8(P3[0], P3[1], P3[2], P3[3]), z16, 0, 0, 0);
            acc = __builtin_amdgcn_mfma_f32_32x32x16_f16(aW3b, mk8(P3[4], P3[5], P3[6], P3[7]), acc, 0, 0, 0);
            w4 = acc[0]; w5 = acc[1];
            float y2 = acc[2], y3 = acc[3];
            plswapf(w0, w4); plswapf(w1, w5); plswapf(w2, y2); plswapf(w3, y3);
        }

        // ---- projection G0 -----------------------------------------------------
        bool act;
        {
            float s0 = v0, s1 = v1, s2 = v2, s3 = v3, s4 = v4, s5 = v5;
            CE(s0, s5) CE(s1, s3) CE(s2, s4)
            CE(s1, s2) CE(s3, s4)
            CE(s0, s3) CE(s2, s5)
            CE(s0, s1) CE(s2, s3) CE(s4, s5)
            CE(s1, s2) CE(s3, s4)
            float css = s0 - 1.0f;
            const float t1 = css;
            css += s1; const float t2 = css * 0.5f;
            css += s2; const float t3 = css * (1.0f / 3.0f);
            css += s3; const float t4 = css * 0.25f;
            css += s4; const float t5 = css * 0.2f;
            css += s5; const float t6 = css * (1.0f / 6.0f);
            const float theta = fmaxf(fmaxf(fmaxf(t1, t2), t3), fmaxf(fmaxf(t4, t5), t6));
            const unsigned thw = pkrtz(theta, theta);
            const unsigned vw0 = pkrtz(v0, v1), vw1 = pkrtz(v2, v3), vw2 = pkrtz(v4, v5);
            const unsigned nq0 = h2u(__builtin_elementwise_max(u2h(vw0) - u2h(thw), zero2));
            const unsigned nq1 = h2u(__builtin_elementwise_max(u2h(vw1) - u2h(thw), zero2));
            const unsigned nq2 = h2u(__builtin_elementwise_max(u2h(vw2) - u2h(thw), zero2));
            const fp16x2 d0 = u2h(nq0) - u2h(qA0);
            const fp16x2 d1 = u2h(nq1) - u2h(qA1);
            const fp16x2 d2 = u2h(nq2) - u2h(qA2);
            fp16x2 ad = __builtin_elementwise_max(
                            __builtin_elementwise_max(__builtin_elementwise_max(d0, -d0),
                                                      __builtin_elementwise_max(d1, -d1)),
                            __builtin_elementwise_max(d2, -d2));
            const unsigned rb = h2u(ad);
            act = ((rb & 0xffffu) > T16BITS) | ((rb >> 16) > T16BITS);
            qA0 = nq0; qA1 = nq1; qA2 = nq2;
        }
        // ---- projection G1 -----------------------------------------------------
        {
            float s0 = w0, s1 = w1, s2 = w2, s3 = w3, s4 = w4, s5 = w5;
            CE(s0, s5) CE(s1, s3) CE(s2, s4)
            CE(s1, s2) CE(s3, s4)
            CE(s0, s3) CE(s2, s5)
            CE(s0, s1) CE(s2, s3) CE(s4, s5)
            CE(s1, s2) CE(s3, s4)
            float css = s0 - 1.0f;
            const float t1 = css;
            css += s1; const float t2 = css * 0.5f;
            css += s2; const float t3 = css * (1.0f / 3.0f);
            css += s3; const float t4 = css * 0.25f;
            css += s4; const float t5 = css * 0.2f;
            css += s5; const float t6 = css * (1.0f / 6.0f);
            const float theta = fmaxf(fmaxf(fmaxf(t1, t2), t3), fmaxf(fmaxf(t4, t5), t6));
            const unsigned thw = pkrtz(theta, theta);
            const unsigned vw0 = pkrtz(w0, w1), vw1 = pkrtz(w2, w3), vw2 = pkrtz(w4, w5);
            const unsigned nq0 = h2u(__builtin_elementwise_max(u2h(vw0) - u2h(thw), zero2));
            const unsigned nq1 = h2u(__builtin_elementwise_max(u2h(vw1) - u2h(thw), zero2));
            const unsigned nq2 = h2u(__builtin_elementwise_max(u2h(vw2) - u2h(thw), zero2));
            const fp16x2 d0 = u2h(nq0) - u2h(qB0);
            const fp16x2 d1 = u2h(nq1) - u2h(qB1);
            const fp16x2 d2 = u2h(nq2) - u2h(qB2);
            fp16x2 ad = __builtin_elementwise_max(
                            __builtin_elementwise_max(__builtin_elementwise_max(d0, -d0),
                                                      __builtin_elementwise_max(d1, -d1)),
                            __builtin_elementwise_max(d2, -d2));
            const unsigned rb = h2u(ad);
            act = act | ((rb & 0xffffu) > T16BITS) | ((rb >> 16) > T16BITS);
            qB0 = nq0; qB1 = nq1; qB2 = nq2;
        }

        if (conv || k > KMAX) break;          // this step was the output step
        conv = !__any(act);                   // 128-row granularity

        // in-place uf updates: u words via cndmask; Qd/ONEH words flow through
        uf0 = mk8(ishi ? getw(uf0, 0) : qA0,
                  ishi ? getw(uf0, 1) : qA1,
                  ishi ? getw(uf0, 2) : qA2,
                  getw(uf0, 3));
        uf1 = mk8(ishi ? qA0 : getw(uf1, 0),
                  ishi ? qA1 : getw(uf1, 1),
                  ishi ? qA2 : getw(uf1, 2),
                  getw(uf1, 3));
        uf2 = mk8(ishi ? getw(uf2, 0) : qB0,
                  ishi ? getw(uf2, 1) : qB1,
                  ishi ? getw(uf2, 2) : qB2,
                  getw(uf2, 3));
        uf3 = mk8(ishi ? qB0 : getw(uf3, 0),
                  ishi ? qB1 : getw(uf3, 1),
                  ishi ? qB2 : getw(uf3, 2),
                  getw(uf3, 3));
    }

    // ---------------- store (unpack packed u; 24 B per row, both groups) --------
    {
        const fp16x2 a0 = u2h(qA0), a1 = u2h(qA1), a2 = u2h(qA2);
        float2* o2 = (float2*)(out + own0 * 6);
        o2[0] = make_float2((float)a0[0], (float)a0[1]);
        o2[1] = make_float2((float)a1[0], (float)a1[1]);
        o2[2] = make_float2((float)a2[0], (float)a2[1]);
    }
    {
        const fp16x2 a0 = u2h(qB0), a1 = u2h(qB1), a2 = u2h(qB2);
        float2* o2 = (float2*)(out + own1 * 6);
        o2[0] = make_float2((float)a0[0], (float)a0[1]);
        o2[1] = make_float2((float)a1[0], (float)a1[1]);
        o2[2] = make_float2((float)a2[0], (float)a2[1]);
    }
}

extern "C" void kernel_launch(void* const* d_in, const int* in_sizes, int n_in,
                              void* d_out, int out_size, void* d_ws, size_t ws_size,
                              hipStream_t stream) {
    const float* dptr = (const float*)d_in[0];
    const float* W1   = (const float*)d_in[1];
    const float* b1   = (const float*)d_in[2];
    const float* W2   = (const float*)d_in[3];
    const float* b2   = (const float*)d_in[4];
    const float* W3   = (const float*)d_in[5];
    const float* b3   = (const float*)d_in[6];
    float* out = (float*)d_out;

    const long long B = in_sizes[0] / 3;            // 1048576
    const int rowsPerBlock = 128;                   // 1 wave x 128 rows (2 groups)
    const int grid = (int)((B + rowsPerBlock - 1) / rowsPerBlock);
    nfpn_mfma_kernel<<<grid, 64, 0, stream>>>(dptr, W1, b1, W2, b2, W3, b3, out, B);
}

// Round 17
// 34.283 us; speedup vs baseline: 1.0585x; 1.0585x over previous
//
#include <hip/hip_runtime.h>

typedef _Float16 half8  __attribute__((ext_vector_type(8)));
typedef __fp16   fp16x2 __attribute__((ext_vector_type(2)));
typedef unsigned u32x2  __attribute__((ext_vector_type(2)));
typedef float    f32x16 __attribute__((ext_vector_type(16)));

#define T16BITS 0x1C19u   // f16 bits of ~4.001e-3 (residual stop threshold)
#define KMAX    20        // cap never binds (verified R15: identical output vs 100)
// descending compare-exchange
#define CE(a,b) { float _hi = fmaxf(a,b), _lo = fminf(a,b); a = _hi; b = _lo; }

// permlane32 swap: a' = {a.lo, b.lo}, b' = {a.hi, b.hi}  (lo/hi = lane halves)
static __device__ __forceinline__ void plswap(unsigned &a, unsigned &b) {
#if __has_builtin(__builtin_amdgcn_permlane32_swap)
    u32x2 r = __builtin_amdgcn_permlane32_swap(a, b, false, false);
    a = r[0]; b = r[1];
#else
    unsigned ao, bo;
    asm("v_mov_b32 %0, %2\n\t"
        "v_mov_b32 %1, %3\n\t"
        "v_permlane32_swap_b32 %0, %1"
        : "=&v"(ao), "=&v"(bo) : "v"(a), "v"(b));
    a = ao; b = bo;
#endif
}
static __device__ __forceinline__ void plswapf(float &a, float &b) {
    union { float f; unsigned u; } ua, ub;
    ua.f = a; ub.f = b;
    plswap(ua.u, ub.u);
    a = ua.f; b = ub.f;
}

static __device__ __forceinline__ unsigned pkrtz(float a, float b) {
    union { fp16x2 h; unsigned u; } x;
    x.h = __builtin_amdgcn_cvt_pkrtz(a, b);   // lo = a, hi = b
    return x.u;
}
static __device__ __forceinline__ fp16x2 u2h(unsigned v) {
    union { unsigned u; fp16x2 h; } x; x.u = v; return x.h;
}
static __device__ __forceinline__ unsigned h2u(fp16x2 v) {
    union { fp16x2 h; unsigned u; } x; x.h = v; return x.u;
}
// pack to f16 then packed leaky-relu: max(p, p*0.1)
static __device__ __forceinline__ unsigned pk_leaky(float a, float b, fp16x2 slope) {
    union { fp16x2 h; unsigned u; } x;
    x.h = __builtin_amdgcn_cvt_pkrtz(a, b);
    fp16x2 m = x.h * slope;
    x.h = __builtin_elementwise_max(x.h, m);
    return x.u;
}
static __device__ __forceinline__ unsigned pk_rne(float a, float b) {
    union { _Float16 h[2]; unsigned u; } x;
    x.h[0] = (_Float16)a; x.h[1] = (_Float16)b;
    return x.u;
}
static __device__ __forceinline__ half8 mk8(unsigned a, unsigned b, unsigned c, unsigned d) {
    union { unsigned u[4]; half8 h; } x;
    x.u[0] = a; x.u[1] = b; x.u[2] = c; x.u[3] = d;
    return x.h;
}
// extract word i (compile-time const) of a half8
static __device__ __forceinline__ unsigned getw(half8 v, int i) {
    union { half8 h; unsigned u[4]; } x; x.h = v; return x.u[i];
}

__launch_bounds__(256, 6)
__global__ void nfpn_mfma_kernel(const float* __restrict__ dptr,
                                 const float* __restrict__ W1, const float* __restrict__ b1,
                                 const float* __restrict__ W2, const float* __restrict__ b2,
                                 const float* __restrict__ W3, const float* __restrict__ b3,
                                 float* __restrict__ out, long long B)
{
    const int lane = threadIdx.x & 63;
    const int hi   = lane >> 5;          // lane half (0: lanes 0-31, 1: lanes 32-63)
    const int col  = lane & 31;          // MFMA column / M-row index
    const bool ishi = (hi != 0);
    const long long wid = ((long long)blockIdx.x * blockDim.x + threadIdx.x) >> 6;
    const long long own = wid * 64 + (long long)hi * 32 + col;   // this lane's batch row
    if (own >= B) return;                // B % 256 == 0 -> wave-uniform

    // ---------------- SINGLE A1 fragment (both tiles share it, R9 choreography) -
    // slot k = 8*hi + e: k0..5 = u, k6..11 = Qd, k12 = b2-slot(1.0)
    half8 aW2;
    {
        unsigned w[4];
        const bool jv = (col < 30);
        const int jc = jv ? col : 0;
        #pragma unroll
        for (int i = 0; i < 4; ++i) {
            const int k0 = 8 * hi + 2 * i, k1 = k0 + 1;
            float x = (k0 < 12) ? W2[jc * 12 + k0] : ((k0 == 12) ? b2[jc] : 0.0f);
            float y = (k1 < 12) ? W2[jc * 12 + k1] : ((k1 == 12) ? b2[jc] : 0.0f);
            if (!jv) { x = 0.0f; y = 0.0f; }
            w[i] = pk_rne(x, y);
        }
        aW2 = mk8(w[0], w[1], w[2], w[3]);
    }

    // ---------------- A2 fragments: k-map = P's NATURAL C-layout word order -----
    // sigma(hi,e) = 4*hi + (e<4 ? e : e+4); A2a row = sigma, A2b row = 16+sigma
    // (negated W3, -b3 at row 30 -> MFMA2 output is projection input v directly)
    half8 aW3a, aW3b;
    {
        unsigned pa[4], pb[4];
        const bool mv = (col < 6);
        const int mc = mv ? col : 0;
        #pragma unroll
        for (int i = 0; i < 4; ++i) {
            const int e0 = 2 * i, e1 = 2 * i + 1;
            const int r0 = 4 * hi + (e0 < 4 ? e0 : e0 + 4);
            const int r1 = 4 * hi + (e1 < 4 ? e1 : e1 + 4);
            float xa = -W3[mc * 30 + r0];    // r0,r1 in [0,16)
            float ya = -W3[mc * 30 + r1];
            if (!mv) { xa = 0.0f; ya = 0.0f; }
            pa[i] = pk_rne(xa, ya);
            const int rb0 = 16 + r0, rb1 = 16 + r1;
            float xb = (rb0 < 30) ? -W3[mc * 30 + rb0] : ((rb0 == 30) ? -b3[mc] : 0.0f);
            float yb = (rb1 < 30) ? -W3[mc * 30 + rb1] : ((rb1 == 30) ? -b3[mc] : 0.0f);
            if (!mv) { xb = 0.0f; yb = 0.0f; }
            pb[i] = pk_rne(xb, yb);
        }
        aW3a = mk8(pa[0], pa[1], pa[2], pa[3]);
        aW3b = mk8(pb[0], pb[1], pb[2], pb[3]);
    }

    const unsigned ONEH = 0x00003C00u;      // f16 {1.0, 0.0}
    const fp16x2 slope = { (__fp16)0.1f, (__fp16)0.1f };
    const fp16x2 zero2 = { (__fp16)0.0f, (__fp16)0.0f };

    // ---------------- initial uf build (Qd lives inside the tuples) -------------
    // uf0/uf1 have IDENTICAL slot structure (shared aW2):
    //   lo words = (u01,u23,u45,Qd01); hi words = (Qd23,Qd45,ONEH,Qd01)
    half8 uf0, uf1;
    {
        const float d0 = dptr[own * 3 + 0], d1 = dptr[own * 3 + 1], d2 = dptr[own * 3 + 2];
        float q0v[6], q1v[6];
        #pragma unroll
        for (int m = 0; m < 6; ++m) {
            float q = fmaf(W1[m * 3 + 0], d0,
                      fmaf(W1[m * 3 + 1], d1,
                      fmaf(W1[m * 3 + 2], d2, b1[m])));
            q0v[m] = __shfl(q, col);        // tile0 col's Qd[m] on all lanes
            q1v[m] = __shfl(q, 32 + col);   // tile1 col's Qd[m] on all lanes
        }
        const unsigned qdA0 = pkrtz(q0v[0], q0v[1]), qdB0 = pkrtz(q0v[2], q0v[3]), qdC0 = pkrtz(q0v[4], q0v[5]);
        const unsigned qdA1 = pkrtz(q1v[0], q1v[1]), qdB1 = pkrtz(q1v[2], q1v[3]), qdC1 = pkrtz(q1v[4], q1v[5]);
        uf0 = mk8(ishi ? qdB0 : 0u, ishi ? qdC0 : 0u, ishi ? ONEH : 0u, qdA0);
        uf1 = mk8(ishi ? qdB1 : 0u, ishi ? qdC1 : 0u, ishi ? ONEH : 0u, qdA1);
    }

    // shared zero C-operand
    f32x16 z16;
    #pragma unroll
    for (int i = 0; i < 16; ++i) z16[i] = 0.0f;

    // u kept packed: (u0,u1)(u2,u3)(u4,u5) f16 words for this lane's own row
    unsigned q0 = 0, q1 = 0, q2 = 0;

    bool conv = false;
    int k = 0;
    #pragma unroll 1
    while (true) {
        ++k;
        // ---- tile0: full pipeline (only acc[0..3] survives -> minimal peak) ----
        float v0, v1, v2, v3;
        {
            f32x16 h = __builtin_amdgcn_mfma_f32_32x32x16_f16(aW2, uf0, z16, 0, 0, 0);
            unsigned P[8];
            #pragma unroll
            for (int i = 0; i < 8; ++i) P[i] = pk_leaky(h[2 * i], h[2 * i + 1], slope);
            P[7] = ishi ? ONEH : P[7];
            f32x16 acc = __builtin_amdgcn_mfma_f32_32x32x16_f16(aW3a, mk8(P[0], P[1], P[2], P[3]), z16, 0, 0, 0);
            acc = __builtin_amdgcn_mfma_f32_32x32x16_f16(aW3b, mk8(P[4], P[5], P[6], P[7]), acc, 0, 0, 0);
            v0 = acc[0]; v1 = acc[1]; v2 = acc[2]; v3 = acc[3];
        }
        // ---- tile1: full pipeline ----------------------------------------------
        float v4, v5, y2, y3;
        {
            f32x16 h = __builtin_amdgcn_mfma_f32_32x32x16_f16(aW2, uf1, z16, 0, 0, 0);
            unsigned P[8];
            #pragma unroll
            for (int i = 0; i < 8; ++i) P[i] = pk_leaky(h[2 * i], h[2 * i + 1], slope);
            P[7] = ishi ? ONEH : P[7];
            f32x16 acc = __builtin_amdgcn_mfma_f32_32x32x16_f16(aW3a, mk8(P[0], P[1], P[2], P[3]), z16, 0, 0, 0);
            acc = __builtin_amdgcn_mfma_f32_32x32x16_f16(aW3b, mk8(P[4], P[5], P[6], P[7]), acc, 0, 0, 0);
            v4 = acc[0]; v5 = acc[1]; y2 = acc[2]; y3 = acc[3];
        }

        // gather v0..v5 of this lane's own element (lo lanes: tile0, hi: tile1)
        plswapf(v0, v4);
        plswapf(v1, v5);
        plswapf(v2, y2);
        plswapf(v3, y3);

        // simplex projection; optimal 12-comparator sort network (desc), fp32
        float s0 = v0, s1 = v1, s2 = v2, s3 = v3, s4 = v4, s5 = v5;
        CE(s0, s5) CE(s1, s3) CE(s2, s4)
        CE(s1, s2) CE(s3, s4)
        CE(s0, s3) CE(s2, s5)
        CE(s0, s1) CE(s2, s3) CE(s4, s5)
        CE(s1, s2) CE(s3, s4)
        // theta = max_k (prefix_k - 1)/k   (Condat max identity)
        float css = s0 - 1.0f;
        const float t1 = css;
        css += s1; const float t2 = css * 0.5f;
        css += s2; const float t3 = css * (1.0f / 3.0f);
        css += s3; const float t4 = css * 0.25f;
        css += s4; const float t5 = css * 0.2f;
        css += s5; const float t6 = css * (1.0f / 6.0f);
        const float theta = fmaxf(fmaxf(fmaxf(t1, t2), t3), fmaxf(fmaxf(t4, t5), t6));

        // packed update: u_new = relu(v - theta) in f16 pairs
        const unsigned thw = pkrtz(theta, theta);
        const unsigned vw0 = pkrtz(v0, v1), vw1 = pkrtz(v2, v3), vw2 = pkrtz(v4, v5);
        const unsigned nq0 = h2u(__builtin_elementwise_max(u2h(vw0) - u2h(thw), zero2));
        const unsigned nq1 = h2u(__builtin_elementwise_max(u2h(vw1) - u2h(thw), zero2));
        const unsigned nq2 = h2u(__builtin_elementwise_max(u2h(vw2) - u2h(thw), zero2));

        // packed residual |u_new - u_old|, threshold via integer compare on f16 bits
        const fp16x2 d0 = u2h(nq0) - u2h(q0);
        const fp16x2 d1 = u2h(nq1) - u2h(q1);
        const fp16x2 d2 = u2h(nq2) - u2h(q2);
        fp16x2 ad = __builtin_elementwise_max(
                        __builtin_elementwise_max(__builtin_elementwise_max(d0, -d0),
                                                  __builtin_elementwise_max(d1, -d1)),
                        __builtin_elementwise_max(d2, -d2));
        const unsigned rb = h2u(ad);
        const bool act = ((rb & 0xffffu) > T16BITS) | ((rb >> 16) > T16BITS);

        q0 = nq0; q1 = nq1; q2 = nq2;

        if (conv || k > KMAX) break;          // this step was the output step
        conv = !__any(act);                   // 64-row granularity

        // route u to both tiles (R9-verified): t'_lo-lanes = hi-half's u (tile1)
        unsigned t0 = q0, t1_ = q1, t2_ = q2;
        {
            unsigned a0 = q0, a1 = q1, a2 = q2;
            plswap(a0, t0);
            plswap(a1, t1_);
            plswap(a2, t2_);
        }
        // in-place uf update: u words via cndmask; Qd/ONEH words flow through
        uf0 = mk8(ishi ? getw(uf0, 0) : q0,
                  ishi ? getw(uf0, 1) : q1,
                  ishi ? getw(uf0, 2) : q2,
                  getw(uf0, 3));
        uf1 = mk8(ishi ? getw(uf1, 0) : t0,
                  ishi ? getw(uf1, 1) : t1_,
                  ishi ? getw(uf1, 2) : t2_,
                  getw(uf1, 3));
    }

    // ---------------- store (unpack packed u; 24 B per row) ---------------------
    const fp16x2 a0 = u2h(q0), a1 = u2h(q1), a2 = u2h(q2);
    float2* o2 = (float2*)(out + own * 6);
    o2[0] = make_float2((float)a0[0], (float)a0[1]);
    o2[1] = make_float2((float)a1[0], (float)a1[1]);
    o2[2] = make_float2((float)a2[0], (float)a2[1]);
}

extern "C" void kernel_launch(void* const* d_in, const int* in_sizes, int n_in,
                              void* d_out, int out_size, void* d_ws, size_t ws_size,
                              hipStream_t stream) {
    const float* dptr = (const float*)d_in[0];
    const float* W1   = (const float*)d_in[1];
    const float* b1   = (const float*)d_in[2];
    const float* W2   = (const float*)d_in[3];
    const float* b2   = (const float*)d_in[4];
    const float* W3   = (const float*)d_in[5];
    const float* b3   = (const float*)d_in[6];
    float* out = (float*)d_out;

    const long long B = in_sizes[0] / 3;            // 1048576
    const int rowsPerBlock = 256;                   // 4 waves x 64 rows
    const int grid = (int)((B + rowsPerBlock - 1) / rowsPerBlock);
    nfpn_mfma_kernel<<<grid, 256, 0, stream>>>(dptr, W1, b1, W2, b2, W3, b3, out, B);
}

// Round 18
// 33.772 us; speedup vs baseline: 1.0745x; 1.0151x over previous
//
#include <hip/hip_runtime.h>

typedef _Float16 half8  __attribute__((ext_vector_type(8)));
typedef __fp16   fp16x2 __attribute__((ext_vector_type(2)));
typedef unsigned u32x2  __attribute__((ext_vector_type(2)));
typedef float    f32x16 __attribute__((ext_vector_type(16)));

#define T16BITS 0x1C19u   // f16 bits of ~4.001e-3 (residual stop threshold)
#define KMAX    20        // cap never binds (verified R15: identical output vs 100)
// descending compare-exchange
#define CE(a,b) { float _hi = fmaxf(a,b), _lo = fminf(a,b); a = _hi; b = _lo; }

// permlane32 swap: a' = {a.lo, b.lo}, b' = {a.hi, b.hi}  (lo/hi = lane halves)
static __device__ __forceinline__ void plswap(unsigned &a, unsigned &b) {
#if __has_builtin(__builtin_amdgcn_permlane32_swap)
    u32x2 r = __builtin_amdgcn_permlane32_swap(a, b, false, false);
    a = r[0]; b = r[1];
#else
    unsigned ao, bo;
    asm("v_mov_b32 %0, %2\n\t"
        "v_mov_b32 %1, %3\n\t"
        "v_permlane32_swap_b32 %0, %1"
        : "=&v"(ao), "=&v"(bo) : "v"(a), "v"(b));
    a = ao; b = bo;
#endif
}
static __device__ __forceinline__ void plswapf(float &a, float &b) {
    union { float f; unsigned u; } ua, ub;
    ua.f = a; ub.f = b;
    plswap(ua.u, ub.u);
    a = ua.f; b = ub.f;
}

static __device__ __forceinline__ unsigned pkrtz(float a, float b) {
    union { fp16x2 h; unsigned u; } x;
    x.h = __builtin_amdgcn_cvt_pkrtz(a, b);   // lo = a, hi = b
    return x.u;
}
static __device__ __forceinline__ fp16x2 u2h(unsigned v) {
    union { unsigned u; fp16x2 h; } x; x.u = v; return x.h;
}
static __device__ __forceinline__ unsigned h2u(fp16x2 v) {
    union { fp16x2 h; unsigned u; } x; x.h = v; return x.u;
}
// pack to f16 then packed leaky-relu: max(p, p*0.1)
static __device__ __forceinline__ unsigned pk_leaky(float a, float b, fp16x2 slope) {
    union { fp16x2 h; unsigned u; } x;
    x.h = __builtin_amdgcn_cvt_pkrtz(a, b);
    fp16x2 m = x.h * slope;
    x.h = __builtin_elementwise_max(x.h, m);
    return x.u;
}
static __device__ __forceinline__ unsigned pk_rne(float a, float b) {
    union { _Float16 h[2]; unsigned u; } x;
    x.h[0] = (_Float16)a; x.h[1] = (_Float16)b;
    return x.u;
}
static __device__ __forceinline__ half8 mk8(unsigned a, unsigned b, unsigned c, unsigned d) {
    union { unsigned u[4]; half8 h; } x;
    x.u[0] = a; x.u[1] = b; x.u[2] = c; x.u[3] = d;
    return x.h;
}
// extract word i (compile-time const) of a half8
static __device__ __forceinline__ unsigned getw(half8 v, int i) {
    union { half8 h; unsigned u[4]; } x; x.h = v; return x.u[i];
}

__launch_bounds__(256, 5)
__global__ void nfpn_mfma_kernel(const float* __restrict__ dptr,
                                 const float* __restrict__ W1, const float* __restrict__ b1,
                                 const float* __restrict__ W2, const float* __restrict__ b2,
                                 const float* __restrict__ W3, const float* __restrict__ b3,
                                 float* __restrict__ out, long long B)
{
    const int lane = threadIdx.x & 63;
    const int hi   = lane >> 5;          // lane half (0: lanes 0-31, 1: lanes 32-63)
    const int col  = lane & 31;          // MFMA column / M-row index
    const bool ishi = (hi != 0);
    const long long wid = ((long long)blockIdx.x * blockDim.x + threadIdx.x) >> 6;
    // two independent row-groups per wave: G0 = rows [wid*128, +64), G1 = +64
    const long long own0 = wid * 128 + (long long)hi * 32 + col;
    const long long own1 = own0 + 64;
    if (own1 >= B) return;               // B % 512 == 0 -> wave-uniform

    // ---------------- SINGLE shared A1 fragment (all 4 tiles, R9 choreography) --
    // slot k = 8*hi + e: k0..5 = u, k6..11 = Qd, k12 = b2-slot(1.0)
    half8 aW2;
    {
        unsigned w[4];
        const bool jv = (col < 30);
        const int jc = jv ? col : 0;
        #pragma unroll
        for (int i = 0; i < 4; ++i) {
            const int k0 = 8 * hi + 2 * i, k1 = k0 + 1;
            float x = (k0 < 12) ? W2[jc * 12 + k0] : ((k0 == 12) ? b2[jc] : 0.0f);
            float y = (k1 < 12) ? W2[jc * 12 + k1] : ((k1 == 12) ? b2[jc] : 0.0f);
            if (!jv) { x = 0.0f; y = 0.0f; }
            w[i] = pk_rne(x, y);
        }
        aW2 = mk8(w[0], w[1], w[2], w[3]);
    }

    // ---------------- A2 fragments: k-map = P's NATURAL C-layout word order -----
    // sigma(hi,e) = 4*hi + (e<4 ? e : e+4); A2a row = sigma, A2b row = 16+sigma
    // (negated W3, -b3 at row 30 -> MFMA2 output is projection input v directly)
    half8 aW3a, aW3b;
    {
        unsigned pa[4], pb[4];
        const bool mv = (col < 6);
        const int mc = mv ? col : 0;
        #pragma unroll
        for (int i = 0; i < 4; ++i) {
            const int e0 = 2 * i, e1 = 2 * i + 1;
            const int r0 = 4 * hi + (e0 < 4 ? e0 : e0 + 4);
            const int r1 = 4 * hi + (e1 < 4 ? e1 : e1 + 4);
            float xa = -W3[mc * 30 + r0];    // r0,r1 in [0,16)
            float ya = -W3[mc * 30 + r1];
            if (!mv) { xa = 0.0f; ya = 0.0f; }
            pa[i] = pk_rne(xa, ya);
            const int rb0 = 16 + r0, rb1 = 16 + r1;
            float xb = (rb0 < 30) ? -W3[mc * 30 + rb0] : ((rb0 == 30) ? -b3[mc] : 0.0f);
            float yb = (rb1 < 30) ? -W3[mc * 30 + rb1] : ((rb1 == 30) ? -b3[mc] : 0.0f);
            if (!mv) { xb = 0.0f; yb = 0.0f; }
            pb[i] = pk_rne(xb, yb);
        }
        aW3a = mk8(pa[0], pa[1], pa[2], pa[3]);
        aW3b = mk8(pb[0], pb[1], pb[2], pb[3]);
    }

    const unsigned ONEH = 0x00003C00u;      // f16 {1.0, 0.0}
    const fp16x2 slope = { (__fp16)0.1f, (__fp16)0.1f };
    const fp16x2 zero2 = { (__fp16)0.0f, (__fp16)0.0f };

    // ---------------- initial uf build, both groups (Qd inside the tuples) ------
    // all ufs share slot structure: lo words = (u01,u23,u45,Qd01);
    //                               hi words = (Qd23,Qd45,ONEH,Qd01)
    half8 uf0, uf1, uf2, uf3;
    {
        const float dA0 = dptr[own0 * 3 + 0], dA1 = dptr[own0 * 3 + 1], dA2 = dptr[own0 * 3 + 2];
        const float dB0 = dptr[own1 * 3 + 0], dB1 = dptr[own1 * 3 + 1], dB2 = dptr[own1 * 3 + 2];
        float qa0[6], qa1[6], qb0[6], qb1[6];
        #pragma unroll
        for (int m = 0; m < 6; ++m) {
            const float w0v = W1[m * 3 + 0], w1v = W1[m * 3 + 1], w2v = W1[m * 3 + 2], bb = b1[m];
            float qa = fmaf(w0v, dA0, fmaf(w1v, dA1, fmaf(w2v, dA2, bb)));
            float qb = fmaf(w0v, dB0, fmaf(w1v, dB1, fmaf(w2v, dB2, bb)));
            qa0[m] = __shfl(qa, col);        // G0 tile0 col's Qd[m]
            qa1[m] = __shfl(qa, 32 + col);   // G0 tile1
            qb0[m] = __shfl(qb, col);        // G1 tile0
            qb1[m] = __shfl(qb, 32 + col);   // G1 tile1
        }
        const unsigned A0 = pkrtz(qa0[0], qa0[1]), B0 = pkrtz(qa0[2], qa0[3]), C0 = pkrtz(qa0[4], qa0[5]);
        const unsigned A1 = pkrtz(qa1[0], qa1[1]), B1 = pkrtz(qa1[2], qa1[3]), C1 = pkrtz(qa1[4], qa1[5]);
        const unsigned A2 = pkrtz(qb0[0], qb0[1]), B2 = pkrtz(qb0[2], qb0[3]), C2 = pkrtz(qb0[4], qb0[5]);
        const unsigned A3 = pkrtz(qb1[0], qb1[1]), B3 = pkrtz(qb1[2], qb1[3]), C3 = pkrtz(qb1[4], qb1[5]);
        uf0 = mk8(ishi ? B0 : 0u, ishi ? C0 : 0u, ishi ? ONEH : 0u, A0);
        uf1 = mk8(ishi ? B1 : 0u, ishi ? C1 : 0u, ishi ? ONEH : 0u, A1);
        uf2 = mk8(ishi ? B2 : 0u, ishi ? C2 : 0u, ishi ? ONEH : 0u, A2);
        uf3 = mk8(ishi ? B3 : 0u, ishi ? C3 : 0u, ishi ? ONEH : 0u, A3);
    }

    // shared zero C-operand
    f32x16 z16;
    #pragma unroll
    for (int i = 0; i < 16; ++i) z16[i] = 0.0f;

    // packed u per group: (u0,u1)(u2,u3)(u4,u5)
    unsigned qA0 = 0, qA1 = 0, qA2 = 0;     // G0
    unsigned qB0 = 0, qB1 = 0, qB2 = 0;     // G1

    // per-tile pipeline: MFMA1 -> packed leaky -> MFMA2 chain; only 4 floats out
    auto tilepipe = [&](const half8 &uf, float &o0, float &o1, float &o2, float &o3) {
        f32x16 h = __builtin_amdgcn_mfma_f32_32x32x16_f16(aW2, uf, z16, 0, 0, 0);
        unsigned P[8];
        #pragma unroll
        for (int i = 0; i < 8; ++i) P[i] = pk_leaky(h[2 * i], h[2 * i + 1], slope);
        P[7] = ishi ? ONEH : P[7];
        f32x16 acc = __builtin_amdgcn_mfma_f32_32x32x16_f16(aW3a, mk8(P[0], P[1], P[2], P[3]), z16, 0, 0, 0);
        acc = __builtin_amdgcn_mfma_f32_32x32x16_f16(aW3b, mk8(P[4], P[5], P[6], P[7]), acc, 0, 0, 0);
        o0 = acc[0]; o1 = acc[1]; o2 = acc[2]; o3 = acc[3];
    };
    // projection + packed update + residual; returns act
    auto project = [&](float p0, float p1, float p2, float p3, float p4, float p5,
                       unsigned &r0, unsigned &r1, unsigned &r2) -> bool {
        float s0 = p0, s1 = p1, s2 = p2, s3 = p3, s4 = p4, s5 = p5;
        CE(s0, s5) CE(s1, s3) CE(s2, s4)
        CE(s1, s2) CE(s3, s4)
        CE(s0, s3) CE(s2, s5)
        CE(s0, s1) CE(s2, s3) CE(s4, s5)
        CE(s1, s2) CE(s3, s4)
        float css = s0 - 1.0f;
        const float t1 = css;
        css += s1; const float t2 = css * 0.5f;
        css += s2; const float t3 = css * (1.0f / 3.0f);
        css += s3; const float t4 = css * 0.25f;
        css += s4; const float t5 = css * 0.2f;
        css += s5; const float t6 = css * (1.0f / 6.0f);
        const float theta = fmaxf(fmaxf(fmaxf(t1, t2), t3), fmaxf(fmaxf(t4, t5), t6));
        const unsigned thw = pkrtz(theta, theta);
        const unsigned vw0 = pkrtz(p0, p1), vw1 = pkrtz(p2, p3), vw2 = pkrtz(p4, p5);
        const unsigned nq0 = h2u(__builtin_elementwise_max(u2h(vw0) - u2h(thw), zero2));
        const unsigned nq1 = h2u(__builtin_elementwise_max(u2h(vw1) - u2h(thw), zero2));
        const unsigned nq2 = h2u(__builtin_elementwise_max(u2h(vw2) - u2h(thw), zero2));
        const fp16x2 d0 = u2h(nq0) - u2h(r0);
        const fp16x2 d1 = u2h(nq1) - u2h(r1);
        const fp16x2 d2 = u2h(nq2) - u2h(r2);
        fp16x2 ad = __builtin_elementwise_max(
                        __builtin_elementwise_max(__builtin_elementwise_max(d0, -d0),
                                                  __builtin_elementwise_max(d1, -d1)),
                        __builtin_elementwise_max(d2, -d2));
        const unsigned rb = h2u(ad);
        r0 = nq0; r1 = nq1; r2 = nq2;
        return ((rb & 0xffffu) > T16BITS) | ((rb >> 16) > T16BITS);
    };

    bool conv = false;
    int k = 0;
    #pragma unroll 1
    while (true) {
        ++k;
        // ---- G0: two sequential tile pipelines (low transient peak) ------------
        float v0, v1, v2, v3, v4, v5, y2, y3;
        tilepipe(uf0, v0, v1, v2, v3);
        tilepipe(uf1, v4, v5, y2, y3);
        plswapf(v0, v4); plswapf(v1, v5); plswapf(v2, y2); plswapf(v3, y3);
        // ---- G1: independent chain (fills G0's MFMA/projection shadows) --------
        float w0, w1, w2, w3, w4, w5, x2, x3;
        tilepipe(uf2, w0, w1, w2, w3);
        tilepipe(uf3, w4, w5, x2, x3);
        plswapf(w0, w4); plswapf(w1, w5); plswapf(w2, x2); plswapf(w3, x3);

        // ---- projections (G0's VALU overlaps G1's MFMA latency) ----------------
        bool act = project(v0, v1, v2, v3, v4, v5, qA0, qA1, qA2);
        act = act | project(w0, w1, w2, w3, w4, w5, qB0, qB1, qB2);

        if (conv || k > KMAX) break;          // this step was the output step
        conv = !__any(act);                   // 128-row granularity

        // route u to tile1 per group (R9-verified), rebuild ufs via cndmask
        unsigned tA0 = qA0, tA1 = qA1, tA2 = qA2;
        { unsigned a0 = qA0, a1 = qA1, a2 = qA2; plswap(a0, tA0); plswap(a1, tA1); plswap(a2, tA2); }
        unsigned tB0 = qB0, tB1 = qB1, tB2 = qB2;
        { unsigned a0 = qB0, a1 = qB1, a2 = qB2; plswap(a0, tB0); plswap(a1, tB1); plswap(a2, tB2); }
        uf0 = mk8(ishi ? getw(uf0, 0) : qA0, ishi ? getw(uf0, 1) : qA1, ishi ? getw(uf0, 2) : qA2, getw(uf0, 3));
        uf1 = mk8(ishi ? getw(uf1, 0) : tA0, ishi ? getw(uf1, 1) : tA1, ishi ? getw(uf1, 2) : tA2, getw(uf1, 3));
        uf2 = mk8(ishi ? getw(uf2, 0) : qB0, ishi ? getw(uf2, 1) : qB1, ishi ? getw(uf2, 2) : qB2, getw(uf2, 3));
        uf3 = mk8(ishi ? getw(uf3, 0) : tB0, ishi ? getw(uf3, 1) : tB1, ishi ? getw(uf3, 2) : tB2, getw(uf3, 3));
    }

    // ---------------- store (unpack packed u; 24 B per row, both groups) --------
    {
        const fp16x2 a0 = u2h(qA0), a1 = u2h(qA1), a2 = u2h(qA2);
        float2* o2 = (float2*)(out + own0 * 6);
        o2[0] = make_float2((float)a0[0], (float)a0[1]);
        o2[1] = make_float2((float)a1[0], (float)a1[1]);
        o2[2] = make_float2((float)a2[0], (float)a2[1]);
    }
    {
        const fp16x2 a0 = u2h(qB0), a1 = u2h(qB1), a2 = u2h(qB2);
        float2* o2 = (float2*)(out + own1 * 6);
        o2[0] = make_float2((float)a0[0], (float)a0[1]);
        o2[1] = make_float2((float)a1[0], (float)a1[1]);
        o2[2] = make_float2((float)a2[0], (float)a2[1]);
    }
}

extern "C" void kernel_launch(void* const* d_in, const int* in_sizes, int n_in,
                              void* d_out, int out_size, void* d_ws, size_t ws_size,
                              hipStream_t stream) {
    const float* dptr = (const float*)d_in[0];
    const float* W1   = (const float*)d_in[1];
    const float* b1   = (const float*)d_in[2];
    const float* W2   = (const float*)d_in[3];
    const float* b2   = (const float*)d_in[4];
    const float* W3   = (const float*)d_in[5];
    const float* b3   = (const float*)d_in[6];
    float* out = (float*)d_out;

    const long long B = in_sizes[0] / 3;            // 1048576
    const int rowsPerBlock = 512;                   // 4 waves x 128 rows (2 groups)
    const int grid = (int)((B + rowsPerBlock - 1) / rowsPerBlock);
    nfpn_mfma_kernel<<<grid, 256, 0, stream>>>(dptr, W1, b1, W2, b2, W3, b3, out, B);
}

// Round 19
// 33.415 us; speedup vs baseline: 1.0860x; 1.0107x over previous
//
#include <hip/hip_runtime.h>

typedef _Float16 half8  __attribute__((ext_vector_type(8)));
typedef __fp16   fp16x2 __attribute__((ext_vector_type(2)));
typedef unsigned u32x2  __attribute__((ext_vector_type(2)));
typedef float    f32x16 __attribute__((ext_vector_type(16)));

#define T16BITS 0x1C19u   // f16 bits of ~4.001e-3 (residual stop threshold)
#define KMAX    20        // cap never binds (verified R15: identical output vs 100)
// descending compare-exchange
#define CE(a,b) { float _hi = fmaxf(a,b), _lo = fminf(a,b); a = _hi; b = _lo; }

// permlane32 swap: a' = {a.lo, b.lo}, b' = {a.hi, b.hi}  (lo/hi = lane halves)
static __device__ __forceinline__ void plswap(unsigned &a, unsigned &b) {
#if __has_builtin(__builtin_amdgcn_permlane32_swap)
    u32x2 r = __builtin_amdgcn_permlane32_swap(a, b, false, false);
    a = r[0]; b = r[1];
#else
    unsigned ao, bo;
    asm("v_mov_b32 %0, %2\n\t"
        "v_mov_b32 %1, %3\n\t"
        "v_permlane32_swap_b32 %0, %1"
        : "=&v"(ao), "=&v"(bo) : "v"(a), "v"(b));
    a = ao; b = bo;
#endif
}
static __device__ __forceinline__ void plswapf(float &a, float &b) {
    union { float f; unsigned u; } ua, ub;
    ua.f = a; ub.f = b;
    plswap(ua.u, ub.u);
    a = ua.f; b = ub.f;
}

static __device__ __forceinline__ unsigned pkrtz(float a, float b) {
    union { fp16x2 h; unsigned u; } x;
    x.h = __builtin_amdgcn_cvt_pkrtz(a, b);   // lo = a, hi = b
    return x.u;
}
static __device__ __forceinline__ fp16x2 u2h(unsigned v) {
    union { unsigned u; fp16x2 h; } x; x.u = v; return x.h;
}
static __device__ __forceinline__ unsigned h2u(fp16x2 v) {
    union { fp16x2 h; unsigned u; } x; x.h = v; return x.u;
}
// pack to f16 then packed leaky-relu: max(p, p*0.1)
static __device__ __forceinline__ unsigned pk_leaky(float a, float b, fp16x2 slope) {
    union { fp16x2 h; unsigned u; } x;
    x.h = __builtin_amdgcn_cvt_pkrtz(a, b);
    fp16x2 m = x.h * slope;
    x.h = __builtin_elementwise_max(x.h, m);
    return x.u;
}
static __device__ __forceinline__ unsigned pk_rne(float a, float b) {
    union { _Float16 h[2]; unsigned u; } x;
    x.h[0] = (_Float16)a; x.h[1] = (_Float16)b;
    return x.u;
}
static __device__ __forceinline__ half8 mk8(unsigned a, unsigned b, unsigned c, unsigned d) {
    union { unsigned u[4]; half8 h; } x;
    x.u[0] = a; x.u[1] = b; x.u[2] = c; x.u[3] = d;
    return x.h;
}
// extract word i (compile-time const) of a half8
static __device__ __forceinline__ unsigned getw(half8 v, int i) {
    union { half8 h; unsigned u[4]; } x; x.h = v; return x.u[i];
}

__launch_bounds__(256, 5)
__global__ void nfpn_mfma_kernel(const float* __restrict__ dptr,
                                 const float* __restrict__ W1, const float* __restrict__ b1,
                                 const float* __restrict__ W2, const float* __restrict__ b2,
                                 const float* __restrict__ W3, const float* __restrict__ b3,
                                 float* __restrict__ out, long long B)
{
    const int lane = threadIdx.x & 63;
    const int hi   = lane >> 5;          // lane half (0: lanes 0-31, 1: lanes 32-63)
    const int col  = lane & 31;          // MFMA column / M-row index
    const bool ishi = (hi != 0);
    const long long wid = ((long long)blockIdx.x * blockDim.x + threadIdx.x) >> 6;
    // two independent row-groups per wave: G0 = rows [wid*128, +64), G1 = +64
    const long long own0 = wid * 128 + (long long)hi * 32 + col;
    const long long own1 = own0 + 64;
    if (own1 >= B) return;               // B % 512 == 0 -> wave-uniform

    // ---------------- SINGLE shared A1 fragment (all 4 tiles, R9 choreography) --
    // slot k = 8*hi + e: k0..5 = u, k6..11 = Qd, k12 = b2-slot(1.0)
    half8 aW2;
    {
        unsigned w[4];
        const bool jv = (col < 30);
        const int jc = jv ? col : 0;
        #pragma unroll
        for (int i = 0; i < 4; ++i) {
            const int k0 = 8 * hi + 2 * i, k1 = k0 + 1;
            float x = (k0 < 12) ? W2[jc * 12 + k0] : ((k0 == 12) ? b2[jc] : 0.0f);
            float y = (k1 < 12) ? W2[jc * 12 + k1] : ((k1 == 12) ? b2[jc] : 0.0f);
            if (!jv) { x = 0.0f; y = 0.0f; }
            w[i] = pk_rne(x, y);
        }
        aW2 = mk8(w[0], w[1], w[2], w[3]);
    }

    // ---------------- A2 fragments: k-map = P's NATURAL C-layout word order -----
    // sigma(hi,e) = 4*hi + (e<4 ? e : e+4); A2a row = sigma, A2b row = 16+sigma
    // (negated W3, -b3 at row 30 -> MFMA2 output is projection input v directly)
    half8 aW3a, aW3b;
    {
        unsigned pa[4], pb[4];
        const bool mv = (col < 6);
        const int mc = mv ? col : 0;
        #pragma unroll
        for (int i = 0; i < 4; ++i) {
            const int e0 = 2 * i, e1 = 2 * i + 1;
            const int r0 = 4 * hi + (e0 < 4 ? e0 : e0 + 4);
            const int r1 = 4 * hi + (e1 < 4 ? e1 : e1 + 4);
            float xa = -W3[mc * 30 + r0];    // r0,r1 in [0,16)
            float ya = -W3[mc * 30 + r1];
            if (!mv) { xa = 0.0f; ya = 0.0f; }
            pa[i] = pk_rne(xa, ya);
            const int rb0 = 16 + r0, rb1 = 16 + r1;
            float xb = (rb0 < 30) ? -W3[mc * 30 + rb0] : ((rb0 == 30) ? -b3[mc] : 0.0f);
            float yb = (rb1 < 30) ? -W3[mc * 30 + rb1] : ((rb1 == 30) ? -b3[mc] : 0.0f);
            if (!mv) { xb = 0.0f; yb = 0.0f; }
            pb[i] = pk_rne(xb, yb);
        }
        aW3a = mk8(pa[0], pa[1], pa[2], pa[3]);
        aW3b = mk8(pb[0], pb[1], pb[2], pb[3]);
    }

    const unsigned ONEH = 0x00003C00u;      // f16 {1.0, 0.0}
    const fp16x2 slope = { (__fp16)0.1f, (__fp16)0.1f };
    const fp16x2 zero2 = { (__fp16)0.0f, (__fp16)0.0f };

    // ---------------- initial uf build, both groups (Qd inside the tuples) ------
    // all ufs share slot structure: lo words = (u01,u23,u45,Qd01);
    //                               hi words = (Qd23,Qd45,ONEH,Qd01)
    half8 uf0, uf1, uf2, uf3;
    {
        const float dA0 = dptr[own0 * 3 + 0], dA1 = dptr[own0 * 3 + 1], dA2 = dptr[own0 * 3 + 2];
        const float dB0 = dptr[own1 * 3 + 0], dB1 = dptr[own1 * 3 + 1], dB2 = dptr[own1 * 3 + 2];
        float qa0[6], qa1[6], qb0[6], qb1[6];
        #pragma unroll
        for (int m = 0; m < 6; ++m) {
            const float w0v = W1[m * 3 + 0], w1v = W1[m * 3 + 1], w2v = W1[m * 3 + 2], bb = b1[m];
            float qa = fmaf(w0v, dA0, fmaf(w1v, dA1, fmaf(w2v, dA2, bb)));
            float qb = fmaf(w0v, dB0, fmaf(w1v, dB1, fmaf(w2v, dB2, bb)));
            qa0[m] = __shfl(qa, col);        // G0 tile0 col's Qd[m]
            qa1[m] = __shfl(qa, 32 + col);   // G0 tile1
            qb0[m] = __shfl(qb, col);        // G1 tile0
            qb1[m] = __shfl(qb, 32 + col);   // G1 tile1
        }
        const unsigned A0 = pkrtz(qa0[0], qa0[1]), B0 = pkrtz(qa0[2], qa0[3]), C0 = pkrtz(qa0[4], qa0[5]);
        const unsigned A1 = pkrtz(qa1[0], qa1[1]), B1 = pkrtz(qa1[2], qa1[3]), C1 = pkrtz(qa1[4], qa1[5]);
        const unsigned A2 = pkrtz(qb0[0], qb0[1]), B2 = pkrtz(qb0[2], qb0[3]), C2 = pkrtz(qb0[4], qb0[5]);
        const unsigned A3 = pkrtz(qb1[0], qb1[1]), B3 = pkrtz(qb1[2], qb1[3]), C3 = pkrtz(qb1[4], qb1[5]);
        uf0 = mk8(ishi ? B0 : 0u, ishi ? C0 : 0u, ishi ? ONEH : 0u, A0);
        uf1 = mk8(ishi ? B1 : 0u, ishi ? C1 : 0u, ishi ? ONEH : 0u, A1);
        uf2 = mk8(ishi ? B2 : 0u, ishi ? C2 : 0u, ishi ? ONEH : 0u, A2);
        uf3 = mk8(ishi ? B3 : 0u, ishi ? C3 : 0u, ishi ? ONEH : 0u, A3);
    }

    // shared zero C-operand
    f32x16 z16;
    #pragma unroll
    for (int i = 0; i < 16; ++i) z16[i] = 0.0f;

    // packed u per group: (u0,u1)(u2,u3)(u4,u5)
    unsigned qA0 = 0, qA1 = 0, qA2 = 0;     // G0
    unsigned qB0 = 0, qB1 = 0, qB2 = 0;     // G1

    // per-tile pipeline: MFMA1 -> packed leaky -> MFMA2 chain; only 4 floats out
    auto tilepipe = [&](const half8 &uf, float &o0, float &o1, float &o2, float &o3) {
        f32x16 h = __builtin_amdgcn_mfma_f32_32x32x16_f16(aW2, uf, z16, 0, 0, 0);
        unsigned P[8];
        #pragma unroll
        for (int i = 0; i < 8; ++i) P[i] = pk_leaky(h[2 * i], h[2 * i + 1], slope);
        P[7] = ishi ? ONEH : P[7];
        f32x16 acc = __builtin_amdgcn_mfma_f32_32x32x16_f16(aW3a, mk8(P[0], P[1], P[2], P[3]), z16, 0, 0, 0);
        acc = __builtin_amdgcn_mfma_f32_32x32x16_f16(aW3b, mk8(P[4], P[5], P[6], P[7]), acc, 0, 0, 0);
        o0 = acc[0]; o1 = acc[1]; o2 = acc[2]; o3 = acc[3];
    };
    // projection + packed update + residual; returns act
    auto project = [&](float p0, float p1, float p2, float p3, float p4, float p5,
                       unsigned &r0, unsigned &r1, unsigned &r2) -> bool {
        float s0 = p0, s1 = p1, s2 = p2, s3 = p3, s4 = p4, s5 = p5;
        CE(s0, s5) CE(s1, s3) CE(s2, s4)
        CE(s1, s2) CE(s3, s4)
        CE(s0, s3) CE(s2, s5)
        CE(s0, s1) CE(s2, s3) CE(s4, s5)
        CE(s1, s2) CE(s3, s4)
        float css = s0 - 1.0f;
        const float t1 = css;
        css += s1; const float t2 = css * 0.5f;
        css += s2; const float t3 = css * (1.0f / 3.0f);
        css += s3; const float t4 = css * 0.25f;
        css += s4; const float t5 = css * 0.2f;
        css += s5; const float t6 = css * (1.0f / 6.0f);
        const float theta = fmaxf(fmaxf(fmaxf(t1, t2), t3), fmaxf(fmaxf(t4, t5), t6));
        const unsigned thw = pkrtz(theta, theta);
        const unsigned vw0 = pkrtz(p0, p1), vw1 = pkrtz(p2, p3), vw2 = pkrtz(p4, p5);
        const unsigned nq0 = h2u(__builtin_elementwise_max(u2h(vw0) - u2h(thw), zero2));
        const unsigned nq1 = h2u(__builtin_elementwise_max(u2h(vw1) - u2h(thw), zero2));
        const unsigned nq2 = h2u(__builtin_elementwise_max(u2h(vw2) - u2h(thw), zero2));
        const fp16x2 d0 = u2h(nq0) - u2h(r0);
        const fp16x2 d1 = u2h(nq1) - u2h(r1);
        const fp16x2 d2 = u2h(nq2) - u2h(r2);
        fp16x2 ad = __builtin_elementwise_max(
                        __builtin_elementwise_max(__builtin_elementwise_max(d0, -d0),
                                                  __builtin_elementwise_max(d1, -d1)),
                        __builtin_elementwise_max(d2, -d2));
        const unsigned rb = h2u(ad);
        r0 = nq0; r1 = nq1; r2 = nq2;
        return ((rb & 0xffffu) > T16BITS) | ((rb >> 16) > T16BITS);
    };

    // per-group convergence: a finished group does NO further work (wave-uniform
    // branches: conv flags come from __any over the whole wave -> no divergence)
    bool conv0 = false, fin0 = false;
    bool conv1 = false, fin1 = false;
    int k = 0;
    #pragma unroll 1
    while (true) {
        ++k;
        const bool over = (k > KMAX);
        if (!fin0) {
            float v0, v1, v2, v3, v4, v5, y2, y3;
            tilepipe(uf0, v0, v1, v2, v3);
            tilepipe(uf1, v4, v5, y2, y3);
            plswapf(v0, v4); plswapf(v1, v5); plswapf(v2, y2); plswapf(v3, y3);
            const bool act = project(v0, v1, v2, v3, v4, v5, qA0, qA1, qA2);
            if (conv0 || over) {
                fin0 = true;                  // this step was G0's output step
            } else {
                conv0 = !__any(act);          // 64-row granularity
                unsigned tA0 = qA0, tA1 = qA1, tA2 = qA2;
                { unsigned a0 = qA0, a1 = qA1, a2 = qA2; plswap(a0, tA0); plswap(a1, tA1); plswap(a2, tA2); }
                uf0 = mk8(ishi ? getw(uf0, 0) : qA0, ishi ? getw(uf0, 1) : qA1, ishi ? getw(uf0, 2) : qA2, getw(uf0, 3));
                uf1 = mk8(ishi ? getw(uf1, 0) : tA0, ishi ? getw(uf1, 1) : tA1, ishi ? getw(uf1, 2) : tA2, getw(uf1, 3));
            }
        }
        if (!fin1) {
            float w0, w1, w2, w3, w4, w5, x2, x3;
            tilepipe(uf2, w0, w1, w2, w3);
            tilepipe(uf3, w4, w5, x2, x3);
            plswapf(w0, w4); plswapf(w1, w5); plswapf(w2, x2); plswapf(w3, x3);
            const bool act = project(w0, w1, w2, w3, w4, w5, qB0, qB1, qB2);
            if (conv1 || over) {
                fin1 = true;                  // this step was G1's output step
            } else {
                conv1 = !__any(act);
                unsigned tB0 = qB0, tB1 = qB1, tB2 = qB2;
                { unsigned a0 = qB0, a1 = qB1, a2 = qB2; plswap(a0, tB0); plswap(a1, tB1); plswap(a2, tB2); }
                uf2 = mk8(ishi ? getw(uf2, 0) : qB0, ishi ? getw(uf2, 1) : qB1, ishi ? getw(uf2, 2) : qB2, getw(uf2, 3));
                uf3 = mk8(ishi ? getw(uf3, 0) : tB0, ishi ? getw(uf3, 1) : tB1, ishi ? getw(uf3, 2) : tB2, getw(uf3, 3));
            }
        }
        if (fin0 && fin1) break;
    }

    // ---------------- store (unpack packed u; 24 B per row, both groups) --------
    {
        const fp16x2 a0 = u2h(qA0), a1 = u2h(qA1), a2 = u2h(qA2);
        float2* o2 = (float2*)(out + own0 * 6);
        o2[0] = make_float2((float)a0[0], (float)a0[1]);
        o2[1] = make_float2((float)a1[0], (float)a1[1]);
        o2[2] = make_float2((float)a2[0], (float)a2[1]);
    }
    {
        const fp16x2 a0 = u2h(qB0), a1 = u2h(qB1), a2 = u2h(qB2);
        float2* o2 = (float2*)(out + own1 * 6);
        o2[0] = make_float2((float)a0[0], (float)a0[1]);
        o2[1] = make_float2((float)a1[0], (float)a1[1]);
        o2[2] = make_float2((float)a2[0], (float)a2[1]);
    }
}

extern "C" void kernel_launch(void* const* d_in, const int* in_sizes, int n_in,
                              void* d_out, int out_size, void* d_ws, size_t ws_size,
                              hipStream_t stream) {
    const float* dptr = (const float*)d_in[0];
    const float* W1   = (const float*)d_in[1];
    const float* b1   = (const float*)d_in[2];
    const float* W2   = (const float*)d_in[3];
    const float* b2   = (const float*)d_in[4];
    const float* W3   = (const float*)d_in[5];
    const float* b3   = (const float*)d_in[6];
    float* out = (float*)d_out;

    const long long B = in_sizes[0] / 3;            // 1048576
    const int rowsPerBlock = 512;                   // 4 waves x 128 rows (2 groups)
    const int grid = (int)((B + rowsPerBlock - 1) / rowsPerBlock);
    nfpn_mfma_kernel<<<grid, 256, 0, stream>>>(dptr, W1, b1, W2, b2, W3, b3, out, B);
}